// Round 9
// baseline (175.778 us; speedup 1.0000x reference)
//
#include <hip/hip_runtime.h>

#define NE 100000   // edges
#define NN 50000    // nodes

typedef short short8 __attribute__((ext_vector_type(8)));
typedef float f32x4 __attribute__((ext_vector_type(4)));
typedef unsigned short ushort;
typedef unsigned int uint;

__device__ inline ushort f2bf(float f) {
    unsigned int u = __float_as_uint(f);
    u += 0x7FFFu + ((u >> 16) & 1u);
    return (ushort)(u >> 16);
}
__device__ inline float bf2f(ushort u) {
    return __uint_as_float((unsigned int)u << 16);
}

__device__ inline short8 pack_bf8(float4 a, float4 b) {
    short8 r;
    r[0] = (short)f2bf(a.x); r[1] = (short)f2bf(a.y);
    r[2] = (short)f2bf(a.z); r[3] = (short)f2bf(a.w);
    r[4] = (short)f2bf(b.x); r[5] = (short)f2bf(b.y);
    r[6] = (short)f2bf(b.z); r[7] = (short)f2bf(b.w);
    return r;
}

// out = bf16( bf(a) + bf(b) + bf(c) ), elementwise over 8 lanes
__device__ inline short8 add3_bf(short8 a, short8 b, short8 c) {
    short8 o;
    #pragma unroll
    for (int i = 0; i < 8; ++i)
        o[i] = (short)f2bf(bf2f((ushort)a[i]) + bf2f((ushort)b[i]) + bf2f((ushort)c[i]));
    return o;
}

// ---------------------------------------------------------------------------
// Prep: pack weight SLICES into bf16 B-fragment order (24 KB per buffer).
// Fragment layout over [64 k][192 n], slot=(s*12+t)*64+lane, s in {0,1}:
//   wf[slot*8+j] = W_m[row_off + 32s + (lane>>4)*8 + j][n & 63],
//   n = t*16 + (lane&15); m: n<64 -> Wq, <128 -> Wk, else Wv.
// row_off: 0 = edge slice, 64 = src slice, 128 = dst slice.
// ---------------------------------------------------------------------------
__device__ inline void pack192(int slot, const float* Wq, const float* Wk,
                               const float* Wv, int row_off, ushort* wf)
{
    int lane = slot & 63;
    int st = slot >> 6;           // 0..23
    int s = st / 12, t = st % 12;
    int n = t * 16 + (lane & 15);
    int kb = row_off + s * 32 + (lane >> 4) * 8;
    const float* w = (n < 64) ? Wq : (n < 128) ? Wk : Wv;
    int nn = n & 63;
    #pragma unroll
    for (int j = 0; j < 8; ++j)
        wf[(size_t)slot * 8 + j] = f2bf(w[(size_t)(kb + j) * 64 + nn]);
}

__device__ inline void pack_wo_slot(int slot, const float* Wo, ushort* wf)
{
    int lane = slot & 63;
    int st = slot >> 6;
    int s = st / 4, t = st % 4;
    int n = t * 16 + (lane & 15);
    int kb = s * 32 + (lane >> 4) * 8;
    #pragma unroll
    for (int j = 0; j < 8; ++j)
        wf[(size_t)slot * 8 + j] = f2bf(Wo[(size_t)(kb + j) * 64 + n]);
}

__global__ __launch_bounds__(256) void prep_all(
    const float* __restrict__ l1Wq, const float* __restrict__ l1Wk,
    const float* __restrict__ l1Wv, const float* __restrict__ l1Wo,
    const float* __restrict__ l2Wq, const float* __restrict__ l2Wk,
    const float* __restrict__ l2Wv, const float* __restrict__ l2Wo,
    ushort* __restrict__ we1, ushort* __restrict__ we2,
    ushort* __restrict__ wn1s, ushort* __restrict__ wn1d,
    ushort* __restrict__ wn2s, ushort* __restrict__ wn2d,
    ushort* __restrict__ wo1, ushort* __restrict__ wo2)
{
    int idx = blockIdx.x * 256 + threadIdx.x;
    if      (idx < 1536)  pack192(idx,         l1Wq, l1Wk, l1Wv,   0, we1);
    else if (idx < 3072)  pack192(idx - 1536,  l2Wq, l2Wk, l2Wv,   0, we2);
    else if (idx < 4608)  pack192(idx - 3072,  l1Wq, l1Wk, l1Wv,  64, wn1s);
    else if (idx < 6144)  pack192(idx - 4608,  l1Wq, l1Wk, l1Wv, 128, wn1d);
    else if (idx < 7680)  pack192(idx - 6144,  l2Wq, l2Wk, l2Wv,  64, wn2s);
    else if (idx < 9216)  pack192(idx - 7680,  l2Wq, l2Wk, l2Wv, 128, wn2d);
    else if (idx < 9728)  pack_wo_slot(idx - 9216, l1Wo, wo1);
    else if (idx < 10240) pack_wo_slot(idx - 9728, l2Wo, wo2);
}

#define MFMA_B16(a, b, c) c = __builtin_amdgcn_mfma_f32_16x16x32_bf16(a, b, c, 0, 0, 0)
#define GLP const __attribute__((address_space(1))) uint*
#define LDP __attribute__((address_space(3))) uint*

// stage all 24 B fragments (24 KB) once; wave w takes frags w*6..w*6+5
#define STAGE24(buf) do {                                                      \
    const char* gs_ = (const char*)(buf) + (size_t)l * 16;                     \
    _Pragma("unroll")                                                          \
    for (int i_ = 0; i_ < 6; ++i_) {                                           \
        const int fr_ = w * 6 + i_;                                            \
        __builtin_amdgcn_global_load_lds((GLP)(gs_ + (size_t)fr_ * 1024),      \
                                         (LDP)(ldsb + (size_t)fr_ * 1024),    \
                                         16, 0, 0);                            \
    }                                                                          \
} while (0)

#define KSTEP(Areg, si) do {                                                   \
    const char* lb_ = ldsb + (size_t)(si) * 12288 + (size_t)l * 16;            \
    short8 b0_  = *(const short8*)(lb_ + 0);                                   \
    short8 b1_  = *(const short8*)(lb_ + 1024);                                \
    short8 b2_  = *(const short8*)(lb_ + 2048);                                \
    short8 b3_  = *(const short8*)(lb_ + 3072);                                \
    short8 b4_  = *(const short8*)(lb_ + 4096);                                \
    short8 b5_  = *(const short8*)(lb_ + 5120);                                \
    short8 b6_  = *(const short8*)(lb_ + 6144);                                \
    short8 b7_  = *(const short8*)(lb_ + 7168);                                \
    short8 b8_  = *(const short8*)(lb_ + 8192);                                \
    short8 b9_  = *(const short8*)(lb_ + 9216);                                \
    short8 b10_ = *(const short8*)(lb_ + 10240);                               \
    short8 b11_ = *(const short8*)(lb_ + 11264);                               \
    MFMA_B16(Areg, b0_,  c0);  MFMA_B16(Areg, b1_,  c1);                       \
    MFMA_B16(Areg, b2_,  c2);  MFMA_B16(Areg, b3_,  c3);                       \
    MFMA_B16(Areg, b4_,  c4);  MFMA_B16(Areg, b5_,  c5);                       \
    MFMA_B16(Areg, b6_,  c6);  MFMA_B16(Areg, b7_,  c7);                       \
    MFMA_B16(Areg, b8_,  c8);  MFMA_B16(Areg, b9_,  c9);                       \
    MFMA_B16(Areg, b10_, c10); MFMA_B16(Areg, b11_, c11);                      \
} while (0)

// dump n-tile t of acc into wave-private LDS transpose region (stride 200 us)
#define DUMPA(creg, t_lit) do {                                                \
    ushort* p_ = lds_u + wbu + (kg * 4) * 200 + (t_lit) * 16 + r;              \
    p_[0]   = f2bf(creg[0]); p_[200] = f2bf(creg[1]);                          \
    p_[400] = f2bf(creg[2]); p_[600] = f2bf(creg[3]);                          \
} while (0)

// ---------------------------------------------------------------------------
// node_proj: TBL[n][0:192] = [nodef[n] @ Wq_sl | @ Wk_sl | @ Wv_sl] (bf16).
// blockIdx.y picks slice (0 = src, 1 = dst). 64 rows/block, dense A.
// ---------------------------------------------------------------------------
__global__ __launch_bounds__(256) void node_proj(
    const float* __restrict__ nodef,
    const ushort* __restrict__ wsrc, const ushort* __restrict__ wdst,
    ushort* __restrict__ SRC, ushort* __restrict__ DST)
{
    __shared__ __align__(1024) char ldsb[25600];
    const ushort* wfrag = blockIdx.y ? wdst : wsrc;
    ushort*       TBL   = blockIdx.y ? DST  : SRC;

    const int tid = threadIdx.x;
    const int l   = tid & 63;
    const int w   = tid >> 6;
    const int r   = l & 15;
    const int kg  = l >> 4;
    const int n0w = blockIdx.x * 64 + w * 16;

    STAGE24(wfrag);

    const int nr  = n0w + r;
    const int nrc = (nr < NN) ? nr : NN - 1;
    const float* rp = nodef + (size_t)nrc * 64;
    const int koff = kg * 8;
    short8 A0 = pack_bf8(*(const float4*)(rp + koff),      *(const float4*)(rp + koff + 4));
    short8 A1 = pack_bf8(*(const float4*)(rp + 32 + koff), *(const float4*)(rp + 36 + koff));

    f32x4 c0 = (f32x4)(0.f), c1 = (f32x4)(0.f), c2  = (f32x4)(0.f), c3  = (f32x4)(0.f);
    f32x4 c4 = (f32x4)(0.f), c5 = (f32x4)(0.f), c6  = (f32x4)(0.f), c7  = (f32x4)(0.f);
    f32x4 c8 = (f32x4)(0.f), c9 = (f32x4)(0.f), c10 = (f32x4)(0.f), c11 = (f32x4)(0.f);

    __syncthreads();              // B staged
    KSTEP(A0, 0);
    KSTEP(A1, 1);
    __syncthreads();              // all B reads done; reuse LDS for transpose

    ushort* lds_u = (ushort*)ldsb;
    const int wbu = w * 3200;
    DUMPA(c0, 0);  DUMPA(c1, 1);  DUMPA(c2, 2);  DUMPA(c3, 3);
    DUMPA(c4, 4);  DUMPA(c5, 5);  DUMPA(c6, 6);  DUMPA(c7, 7);
    DUMPA(c8, 8);  DUMPA(c9, 9);  DUMPA(c10, 10); DUMPA(c11, 11);
    __builtin_amdgcn_s_waitcnt(0);  // own-wave LDS read-after-write

    const int row16 = l >> 2;
    const int seg   = l & 3;
    const int ng    = n0w + row16;
    if (ng < NN) {
        const ushort* lp = lds_u + wbu + row16 * 200 + seg * 16;
        ushort* op = TBL + (size_t)ng * 192 + seg * 16;
        *(short8*)(op +   0) = *(const short8*)(lp +   0);
        *(short8*)(op +   8) = *(const short8*)(lp +   8);
        *(short8*)(op +  64) = *(const short8*)(lp +  64);
        *(short8*)(op +  72) = *(const short8*)(lp +  72);
        *(short8*)(op + 128) = *(const short8*)(lp + 128);
        *(short8*)(op + 136) = *(const short8*)(lp + 136);
    }
}

// ---------------------------------------------------------------------------
// edge_qkv: q/k/v[e] = efin[e] @ We  +  SRC[src[e]]  +  DST[dst[e]].
// Dense MFMA part (contiguous efin rows), gathers issued up-front so their
// latency hides under the MFMA + transpose.
// ---------------------------------------------------------------------------
__global__ __launch_bounds__(256) void edge_qkv(
    const float* __restrict__ efin, const int* __restrict__ eidx,
    const ushort* __restrict__ SRC, const ushort* __restrict__ DST,
    const ushort* __restrict__ wfrag,
    ushort* __restrict__ qo, ushort* __restrict__ ko, ushort* __restrict__ vo)
{
    __shared__ __align__(1024) char ldsb[25600];

    const int tid = threadIdx.x;
    const int l   = tid & 63;
    const int w   = tid >> 6;
    const int r   = l & 15;
    const int kg  = l >> 4;
    const int e0w = blockIdx.x * 64 + w * 16;

    STAGE24(wfrag);

    // ---- gather role: lane = (row16 = l>>2, seg = l&3); issue EARLY ----
    const int row16 = l >> 2;
    const int seg   = l & 3;
    const int eg    = e0w + row16;
    const int egc   = (eg < NE) ? eg : NE - 1;
    const int srcn  = eidx[egc];
    const int dstn  = eidx[NE + egc];
    const ushort* sp = SRC + (size_t)srcn * 192 + seg * 16;
    const ushort* dp = DST + (size_t)dstn * 192 + seg * 16;
    short8 gq0 = *(const short8*)(sp +   0), gq1 = *(const short8*)(sp +   8);
    short8 gk0 = *(const short8*)(sp +  64), gk1 = *(const short8*)(sp +  72);
    short8 gv0 = *(const short8*)(sp + 128), gv1 = *(const short8*)(sp + 136);
    short8 hq0 = *(const short8*)(dp +   0), hq1 = *(const short8*)(dp +   8);
    short8 hk0 = *(const short8*)(dp +  64), hk1 = *(const short8*)(dp +  72);
    short8 hv0 = *(const short8*)(dp + 128), hv1 = *(const short8*)(dp + 136);

    // ---- A fragments: contiguous efin rows (no gather!) ----
    const int e  = e0w + r;
    const int ec = (e < NE) ? e : NE - 1;
    const float* rp = efin + (size_t)ec * 64;
    const int koff = kg * 8;
    short8 A0 = pack_bf8(*(const float4*)(rp + koff),      *(const float4*)(rp + koff + 4));
    short8 A1 = pack_bf8(*(const float4*)(rp + 32 + koff), *(const float4*)(rp + 36 + koff));

    f32x4 c0 = (f32x4)(0.f), c1 = (f32x4)(0.f), c2  = (f32x4)(0.f), c3  = (f32x4)(0.f);
    f32x4 c4 = (f32x4)(0.f), c5 = (f32x4)(0.f), c6  = (f32x4)(0.f), c7  = (f32x4)(0.f);
    f32x4 c8 = (f32x4)(0.f), c9 = (f32x4)(0.f), c10 = (f32x4)(0.f), c11 = (f32x4)(0.f);

    __syncthreads();
    KSTEP(A0, 0);
    KSTEP(A1, 1);
    __syncthreads();

    ushort* lds_u = (ushort*)ldsb;
    const int wbu = w * 3200;
    DUMPA(c0, 0);  DUMPA(c1, 1);  DUMPA(c2, 2);  DUMPA(c3, 3);
    DUMPA(c4, 4);  DUMPA(c5, 5);  DUMPA(c6, 6);  DUMPA(c7, 7);
    DUMPA(c8, 8);  DUMPA(c9, 9);  DUMPA(c10, 10); DUMPA(c11, 11);
    __builtin_amdgcn_s_waitcnt(0);

    if (eg < NE) {
        const ushort* lp = lds_u + wbu + row16 * 200 + seg * 16;
        ushort* oq = qo + (size_t)eg * 64 + seg * 16;
        ushort* ok = ko + (size_t)eg * 64 + seg * 16;
        ushort* ov = vo + (size_t)eg * 64 + seg * 16;
        *(short8*)(oq + 0) = add3_bf(*(const short8*)(lp +   0), gq0, hq0);
        *(short8*)(oq + 8) = add3_bf(*(const short8*)(lp +   8), gq1, hq1);
        *(short8*)(ok + 0) = add3_bf(*(const short8*)(lp +  64), gk0, hk0);
        *(short8*)(ok + 8) = add3_bf(*(const short8*)(lp +  72), gk1, hk1);
        *(short8*)(ov + 0) = add3_bf(*(const short8*)(lp + 128), gv0, hv0);
        *(short8*)(ov + 8) = add3_bf(*(const short8*)(lp + 136), gv1, hv1);
    }
}

// ---------------------------------------------------------------------------
// Attention: one wave per dst edge; writes result IN PLACE into q (only the
// owning wave ever reads q[e]).
// ---------------------------------------------------------------------------
__global__ __launch_bounds__(256) void attn_kernel(
    const ushort* __restrict__ q, const ushort* __restrict__ kbuf,
    const ushort* __restrict__ vbuf, const int* __restrict__ adj_src,
    ushort* __restrict__ ao)
{
    const int wid  = (blockIdx.x * 256 + threadIdx.x) >> 6;
    const int lane = threadIdx.x & 63;
    if (wid >= NE) return;
    const int e    = wid;
    const int half = lane >> 5;
    const int l32  = lane & 31;

    const int4 nb = *(const int4*)(adj_src + e * 8 + half * 4);
    const int nbr0 = nb.x, nbr1 = nb.y, nbr2 = nb.z, nbr3 = nb.w;

    ushort2 qu = *(const ushort2*)(q + (size_t)e * 64 + l32 * 2);
    const float q0 = bf2f(qu.x), q1 = bf2f(qu.y);

    ushort2 ku0 = *(const ushort2*)(kbuf + (size_t)nbr0 * 64 + l32 * 2);
    ushort2 ku1 = *(const ushort2*)(kbuf + (size_t)nbr1 * 64 + l32 * 2);
    ushort2 ku2 = *(const ushort2*)(kbuf + (size_t)nbr2 * 64 + l32 * 2);
    ushort2 ku3 = *(const ushort2*)(kbuf + (size_t)nbr3 * 64 + l32 * 2);
    ushort2 vu0 = *(const ushort2*)(vbuf + (size_t)nbr0 * 64 + l32 * 2);
    ushort2 vu1 = *(const ushort2*)(vbuf + (size_t)nbr1 * 64 + l32 * 2);
    ushort2 vu2 = *(const ushort2*)(vbuf + (size_t)nbr2 * 64 + l32 * 2);
    ushort2 vu3 = *(const ushort2*)(vbuf + (size_t)nbr3 * 64 + l32 * 2);

    float s0 = q0 * bf2f(ku0.x) + q1 * bf2f(ku0.y);
    float s1 = q0 * bf2f(ku1.x) + q1 * bf2f(ku1.y);
    float s2 = q0 * bf2f(ku2.x) + q1 * bf2f(ku2.y);
    float s3 = q0 * bf2f(ku3.x) + q1 * bf2f(ku3.y);
    s0 += __shfl_xor(s0, 1); s0 += __shfl_xor(s0, 2); s0 += __shfl_xor(s0, 4);
    s1 += __shfl_xor(s1, 1); s1 += __shfl_xor(s1, 2); s1 += __shfl_xor(s1, 4);
    s2 += __shfl_xor(s2, 1); s2 += __shfl_xor(s2, 2); s2 += __shfl_xor(s2, 4);
    s3 += __shfl_xor(s3, 1); s3 += __shfl_xor(s3, 2); s3 += __shfl_xor(s3, 4);
    s0 *= 0.25f; s1 *= 0.25f; s2 *= 0.25f; s3 *= 0.25f;

    float m = fmaxf(fmaxf(s0, s1), fmaxf(s2, s3));
    m = fmaxf(m, __shfl_xor(m, 32));
    float w0 = __expf(s0 - m), w1 = __expf(s1 - m);
    float w2 = __expf(s2 - m), w3 = __expf(s3 - m);
    float den = w0 + w1 + w2 + w3;
    den += __shfl_xor(den, 32);
    const float inv = 1.f / den;

    float ox = 0.f, oy = 0.f;
    ox = fmaf(w0, bf2f(vu0.x), ox); oy = fmaf(w0, bf2f(vu0.y), oy);
    ox = fmaf(w1, bf2f(vu1.x), ox); oy = fmaf(w1, bf2f(vu1.y), oy);
    ox = fmaf(w2, bf2f(vu2.x), ox); oy = fmaf(w2, bf2f(vu2.y), oy);
    ox = fmaf(w3, bf2f(vu3.x), ox); oy = fmaf(w3, bf2f(vu3.y), oy);
    ox = (ox + __shfl_xor(ox, 32)) * inv;
    oy = (oy + __shfl_xor(oy, 32)) * inv;

    if (lane < 32) {
        ushort2 o;
        o.x = f2bf(ox);
        o.y = f2bf(oy);
        *(ushort2*)(ao + (size_t)e * 64 + l32 * 2) = o;
    }
}

// ---------------------------------------------------------------------------
// Wo GEMM via MFMA + fused residual: out = ef_in + attn(bf16) @ Wo.
// ---------------------------------------------------------------------------
__global__ __launch_bounds__(256) void wo_mfma(
    const float* __restrict__ ef_in, const ushort* __restrict__ attn,
    const ushort* __restrict__ wofrag, float* __restrict__ efo)
{
    const int wave = threadIdx.x >> 6;
    const int lane = threadIdx.x & 63;
    const int r  = lane & 15;
    const int kg = lane >> 4;
    const int e0 = blockIdx.x * 64 + wave * 16;
    const int e  = e0 + r;
    const int ec = (e < NE) ? e : NE - 1;

    short8 af0 = *(const short8*)(attn + (size_t)ec * 64 + kg * 8);
    short8 af1 = *(const short8*)(attn + (size_t)ec * 64 + 32 + kg * 8);

    const char* wf = (const char*)wofrag + (size_t)lane * 16;
    f32x4 d0 = (f32x4)(0.f), d1 = (f32x4)(0.f), d2 = (f32x4)(0.f), d3 = (f32x4)(0.f);
    short8 g0 = *(const short8*)(wf + 0 * 1024);
    short8 g1 = *(const short8*)(wf + 1 * 1024);
    short8 g2 = *(const short8*)(wf + 2 * 1024);
    short8 g3 = *(const short8*)(wf + 3 * 1024);
    MFMA_B16(af0, g0, d0); MFMA_B16(af0, g1, d1);
    MFMA_B16(af0, g2, d2); MFMA_B16(af0, g3, d3);
    g0 = *(const short8*)(wf + 4 * 1024);
    g1 = *(const short8*)(wf + 5 * 1024);
    g2 = *(const short8*)(wf + 6 * 1024);
    g3 = *(const short8*)(wf + 7 * 1024);
    MFMA_B16(af1, g0, d0); MFMA_B16(af1, g1, d1);
    MFMA_B16(af1, g2, d2); MFMA_B16(af1, g3, d3);

    const int orow = e0 + kg * 4;
    #pragma unroll
    for (int t = 0; t < 4; ++t) {
        const f32x4 dd = (t == 0) ? d0 : (t == 1) ? d1 : (t == 2) ? d2 : d3;
        const int c = t * 16 + r;
        #pragma unroll
        for (int j = 0; j < 4; ++j) {
            int row = orow + j;
            if (row < NE) {
                size_t off = (size_t)row * 64 + c;
                efo[off] = dd[j] + ef_in[off];
            }
        }
    }
}

// ---------------------------------------------------------------------------
extern "C" void kernel_launch(void* const* d_in, const int* in_sizes, int n_in,
                              void* d_out, int out_size, void* d_ws, size_t ws_size,
                              hipStream_t stream)
{
    const float* nodef   = (const float*)d_in[0];
    const float* ef      = (const float*)d_in[1];
    const int*   eidx    = (const int*)d_in[2];   // [2,E]
    const int*   adj_src = (const int*)d_in[4];
    const float* l1Wq = (const float*)d_in[6];
    const float* l1Wk = (const float*)d_in[7];
    const float* l1Wv = (const float*)d_in[8];
    const float* l1Wo = (const float*)d_in[9];
    const float* l2Wq = (const float*)d_in[10];
    const float* l2Wk = (const float*)d_in[11];
    const float* l2Wv = (const float*)d_in[12];
    const float* l2Wo = (const float*)d_in[13];

    ushort* q   = (ushort*)d_ws;                 // [E,64]  12.8 MB
    ushort* k   = q   + (size_t)NE * 64;
    ushort* v   = k   + (size_t)NE * 64;
    ushort* SRC = v   + (size_t)NE * 64;         // [N,192] 19.2 MB
    ushort* DST = SRC + (size_t)NN * 192;        // [N,192]
    ushort* we1  = DST + (size_t)NN * 192;       // 12288 ushorts (24 KB) each
    ushort* we2  = we1 + 12288;
    ushort* wn1s = we2 + 12288;
    ushort* wn1d = wn1s + 12288;
    ushort* wn2s = wn1d + 12288;
    ushort* wn2d = wn2s + 12288;
    ushort* wo1  = wn2d + 12288;                 // 4096 each
    ushort* wo2  = wo1 + 4096;
    float* out = (float*)d_out;

    dim3 blk(256);
    const int ge = (NE + 63) / 64;    // 1563
    const dim3 gn((NN + 63) / 64, 2); // 782 x 2 (src, dst)
    const int ga = (NE + 3) / 4;      // 25000
    const int gw = (NE + 63) / 64;    // 1563

    prep_all<<<40, blk, 0, stream>>>(l1Wq, l1Wk, l1Wv, l1Wo,
                                     l2Wq, l2Wk, l2Wv, l2Wo,
                                     we1, we2, wn1s, wn1d, wn2s, wn2d, wo1, wo2);

    // ---- layer 1 ----
    node_proj<<<gn, blk, 0, stream>>>(nodef, wn1s, wn1d, SRC, DST);
    edge_qkv<<<ge, blk, 0, stream>>>(ef, eidx, SRC, DST, we1, q, k, v);
    attn_kernel<<<ga, blk, 0, stream>>>(q, k, v, adj_src, q);
    wo_mfma<<<gw, blk, 0, stream>>>(ef, q, wo1, out);
    // ---- layer 2 ----
    node_proj<<<gn, blk, 0, stream>>>(nodef, wn2s, wn2d, SRC, DST);
    edge_qkv<<<ge, blk, 0, stream>>>(out, eidx, SRC, DST, we2, q, k, v);
    attn_kernel<<<ga, blk, 0, stream>>>(q, k, v, adj_src, q);
    wo_mfma<<<gw, blk, 0, stream>>>(out, q, wo2, out);
}

// Round 10
// 172.695 us; speedup vs baseline: 1.0179x; 1.0179x over previous
//
#include <hip/hip_runtime.h>

#define NE 100000   // edges
#define NN 50000    // nodes

typedef short short8 __attribute__((ext_vector_type(8)));
typedef float f32x4 __attribute__((ext_vector_type(4)));
typedef unsigned short ushort;
typedef unsigned int uint;

__device__ inline ushort f2bf(float f) {
    unsigned int u = __float_as_uint(f);
    u += 0x7FFFu + ((u >> 16) & 1u);
    return (ushort)(u >> 16);
}
__device__ inline float bf2f(ushort u) {
    return __uint_as_float((unsigned int)u << 16);
}

__device__ inline short8 pack_bf8(float4 a, float4 b) {
    short8 r;
    r[0] = (short)f2bf(a.x); r[1] = (short)f2bf(a.y);
    r[2] = (short)f2bf(a.z); r[3] = (short)f2bf(a.w);
    r[4] = (short)f2bf(b.x); r[5] = (short)f2bf(b.y);
    r[6] = (short)f2bf(b.z); r[7] = (short)f2bf(b.w);
    return r;
}

// ---------------------------------------------------------------------------
// Prep: pack both layers' QKV (72 frags) + Wo (8 frags) weights into bf16
// B-fragment order: wf[((s*12+t)*64+lane)*8+j] = W[k=32s+(lane>>4)*8+j][n=16t+(lane&15)]
// ---------------------------------------------------------------------------
__device__ inline void pack_qkv_slot(int slot, const float* Wq, const float* Wk,
                                     const float* Wv, ushort* wf)
{
    int lane = slot & 63;
    int st = slot >> 6;
    int s = st / 12, t = st % 12;
    int n = t * 16 + (lane & 15);
    int kb = s * 32 + (lane >> 4) * 8;
    const float* w = (n < 64) ? Wq : (n < 128) ? Wk : Wv;
    int nn = n & 63;
    #pragma unroll
    for (int j = 0; j < 8; ++j)
        wf[(size_t)slot * 8 + j] = f2bf(w[(size_t)(kb + j) * 64 + nn]);
}

__device__ inline void pack_wo_slot(int slot, const float* Wo, ushort* wf)
{
    int lane = slot & 63;
    int st = slot >> 6;
    int s = st / 4, t = st % 4;
    int n = t * 16 + (lane & 15);
    int kb = s * 32 + (lane >> 4) * 8;
    #pragma unroll
    for (int j = 0; j < 8; ++j)
        wf[(size_t)slot * 8 + j] = f2bf(Wo[(size_t)(kb + j) * 64 + n]);
}

__global__ __launch_bounds__(256) void prep_all(
    const float* __restrict__ l1Wq, const float* __restrict__ l1Wk,
    const float* __restrict__ l1Wv, const float* __restrict__ l1Wo,
    const float* __restrict__ l2Wq, const float* __restrict__ l2Wk,
    const float* __restrict__ l2Wv, const float* __restrict__ l2Wo,
    ushort* __restrict__ wf1, ushort* __restrict__ wf2,
    ushort* __restrict__ wo1, ushort* __restrict__ wo2)
{
    int idx = blockIdx.x * 256 + threadIdx.x;
    if (idx < 4608)            pack_qkv_slot(idx,         l1Wq, l1Wk, l1Wv, wf1);
    else if (idx < 9216)       pack_qkv_slot(idx - 4608,  l2Wq, l2Wk, l2Wv, wf2);
    else if (idx < 9728)       pack_wo_slot (idx - 9216,  l1Wo, wo1);
    else if (idx < 10240)      pack_wo_slot (idx - 9728,  l2Wo, wo2);
}

// ---------------------------------------------------------------------------
// PHASE A — gather_pack: build the packed bf16 A-fragment stream.
// Thread = (edge e, quarter p). Reads 64 B from each of {ef[e], nodef[src],
// nodef[dst]} (contiguous per thread), packs to bf16, writes 6 short8 into
// xp[((tile*6 + s)*64 + kg*16 + r)] where tile=e>>4, r=e&15:
//   source c, k-half h=p>>1 -> s = 2c+h; kg = (p&1)*2 and +1.
// Lane-contiguous 16 B slots -> phase B loads them perfectly coalesced.
// ---------------------------------------------------------------------------
__global__ __launch_bounds__(256) void gather_pack(
    const float* __restrict__ efin, const float* __restrict__ nodef,
    const int* __restrict__ eidx, ushort* __restrict__ xp)
{
    const int t = blockIdx.x * 256 + threadIdx.x;
    const int e = t >> 2;
    const int p = t & 3;
    if (e >= NE) return;

    const int src = eidx[e];
    const int dst = eidx[NE + e];
    const float* s0 = efin  + (size_t)e   * 64 + p * 16;
    const float* s1 = nodef + (size_t)src * 64 + p * 16;
    const float* s2 = nodef + (size_t)dst * 64 + p * 16;

    const int tile = e >> 4;
    const int r    = e & 15;
    const int sh   = p >> 1;        // k-half within source
    const int kgA  = (p & 1) * 2;   // first kg this thread covers

    #pragma unroll
    for (int c = 0; c < 3; ++c) {
        const float* sp = (c == 0) ? s0 : (c == 1) ? s1 : s2;
        float4 f0 = *(const float4*)(sp + 0);
        float4 f1 = *(const float4*)(sp + 4);
        float4 f2 = *(const float4*)(sp + 8);
        float4 f3 = *(const float4*)(sp + 12);
        short8 loA = pack_bf8(f0, f1);   // kg = kgA
        short8 loB = pack_bf8(f2, f3);   // kg = kgA+1
        const int s = 2 * c + sh;
        ushort* base = xp + ((size_t)(tile * 6 + s) * 64 + r) * 8;
        *(short8*)(base + (size_t)(kgA    ) * 16 * 8) = loA;
        *(short8*)(base + (size_t)(kgA + 1) * 16 * 8) = loB;
    }
}

// ---------------------------------------------------------------------------
// PHASE B — qkv GEMM (round-7 skeleton, gathers replaced by coalesced A loads)
// ---------------------------------------------------------------------------
#define MFMA_B16(a, b, c) c = __builtin_amdgcn_mfma_f32_16x16x32_bf16(a, b, c, 0, 0, 0)
#define GLP const __attribute__((address_space(1))) uint*
#define LDP __attribute__((address_space(3))) uint*

#define STAGE(ph) do {                                                         \
    const char* gs_ = (const char*)wfrag + (size_t)(ph) * 24576 + (size_t)l * 16; \
    __builtin_amdgcn_global_load_lds((GLP)(gs_ + (size_t)(w*6+0)*1024), (LDP)(ldsb + (size_t)(w*6+0)*1024), 16, 0, 0); \
    __builtin_amdgcn_global_load_lds((GLP)(gs_ + (size_t)(w*6+1)*1024), (LDP)(ldsb + (size_t)(w*6+1)*1024), 16, 0, 0); \
    __builtin_amdgcn_global_load_lds((GLP)(gs_ + (size_t)(w*6+2)*1024), (LDP)(ldsb + (size_t)(w*6+2)*1024), 16, 0, 0); \
    __builtin_amdgcn_global_load_lds((GLP)(gs_ + (size_t)(w*6+3)*1024), (LDP)(ldsb + (size_t)(w*6+3)*1024), 16, 0, 0); \
    __builtin_amdgcn_global_load_lds((GLP)(gs_ + (size_t)(w*6+4)*1024), (LDP)(ldsb + (size_t)(w*6+4)*1024), 16, 0, 0); \
    __builtin_amdgcn_global_load_lds((GLP)(gs_ + (size_t)(w*6+5)*1024), (LDP)(ldsb + (size_t)(w*6+5)*1024), 16, 0, 0); \
} while (0)

#define KSTEP(Areg, si) do {                                                   \
    const char* lb_ = ldsb + (size_t)(si) * 12288 + (size_t)l * 16;            \
    short8 b0_  = *(const short8*)(lb_ + 0);                                   \
    short8 b1_  = *(const short8*)(lb_ + 1024);                                \
    short8 b2_  = *(const short8*)(lb_ + 2048);                                \
    short8 b3_  = *(const short8*)(lb_ + 3072);                                \
    short8 b4_  = *(const short8*)(lb_ + 4096);                                \
    short8 b5_  = *(const short8*)(lb_ + 5120);                                \
    short8 b6_  = *(const short8*)(lb_ + 6144);                                \
    short8 b7_  = *(const short8*)(lb_ + 7168);                                \
    short8 b8_  = *(const short8*)(lb_ + 8192);                                \
    short8 b9_  = *(const short8*)(lb_ + 9216);                                \
    short8 b10_ = *(const short8*)(lb_ + 10240);                               \
    short8 b11_ = *(const short8*)(lb_ + 11264);                               \
    MFMA_B16(Areg, b0_,  c0);  MFMA_B16(Areg, b1_,  c1);                       \
    MFMA_B16(Areg, b2_,  c2);  MFMA_B16(Areg, b3_,  c3);                       \
    MFMA_B16(Areg, b4_,  c4);  MFMA_B16(Areg, b5_,  c5);                       \
    MFMA_B16(Areg, b6_,  c6);  MFMA_B16(Areg, b7_,  c7);                       \
    MFMA_B16(Areg, b8_,  c8);  MFMA_B16(Areg, b9_,  c9);                       \
    MFMA_B16(Areg, b10_, c10); MFMA_B16(Areg, b11_, c11);                      \
} while (0)

#define STORE_T(creg, dstp, cloc) do {                                         \
    ushort* dp_ = (dstp) + (cloc);                                             \
    int row_ = e0 + kg * 4;                                                    \
    if (row_ + 0 < NE) dp_[(size_t)(row_ + 0) * 64] = f2bf(creg[0]);           \
    if (row_ + 1 < NE) dp_[(size_t)(row_ + 1) * 64] = f2bf(creg[1]);           \
    if (row_ + 2 < NE) dp_[(size_t)(row_ + 2) * 64] = f2bf(creg[2]);           \
    if (row_ + 3 < NE) dp_[(size_t)(row_ + 3) * 64] = f2bf(creg[3]);           \
} while (0)

__global__ __launch_bounds__(256) void qkv_mfma(
    const ushort* __restrict__ xp, const ushort* __restrict__ wfrag,
    ushort* __restrict__ qo, ushort* __restrict__ ko, ushort* __restrict__ vo)
{
    __shared__ __align__(1024) char ldsb[24 * 1024];

    const int tid = threadIdx.x;
    const int l   = tid & 63;
    const int w   = tid >> 6;
    const int r   = l & 15;
    const int kg  = l >> 4;
    const int e0  = blockIdx.x * 64 + w * 16;
    const int tile = blockIdx.x * 4 + w;

    STAGE(0);

    // A fragments: perfectly coalesced 16 B/lane loads from the packed stream
    const short8* ap = (const short8*)xp + (size_t)tile * 6 * 64 + l;
    short8 A0 = ap[0 * 64];
    short8 A1 = ap[1 * 64];
    short8 A2 = ap[2 * 64];
    short8 A3 = ap[3 * 64];
    short8 A4 = ap[4 * 64];
    short8 A5 = ap[5 * 64];

    f32x4 c0 = (f32x4)(0.f), c1 = (f32x4)(0.f), c2  = (f32x4)(0.f), c3  = (f32x4)(0.f);
    f32x4 c4 = (f32x4)(0.f), c5 = (f32x4)(0.f), c6  = (f32x4)(0.f), c7  = (f32x4)(0.f);
    f32x4 c8 = (f32x4)(0.f), c9 = (f32x4)(0.f), c10 = (f32x4)(0.f), c11 = (f32x4)(0.f);

    __syncthreads();
    KSTEP(A0, 0);
    KSTEP(A1, 1);
    __syncthreads();
    STAGE(1);
    __syncthreads();
    KSTEP(A2, 0);
    KSTEP(A3, 1);
    __syncthreads();
    STAGE(2);
    __syncthreads();
    KSTEP(A4, 0);
    KSTEP(A5, 1);

    STORE_T(c0,  qo, 0 * 16 + r);
    STORE_T(c1,  qo, 1 * 16 + r);
    STORE_T(c2,  qo, 2 * 16 + r);
    STORE_T(c3,  qo, 3 * 16 + r);
    STORE_T(c4,  ko, 0 * 16 + r);
    STORE_T(c5,  ko, 1 * 16 + r);
    STORE_T(c6,  ko, 2 * 16 + r);
    STORE_T(c7,  ko, 3 * 16 + r);
    STORE_T(c8,  vo, 0 * 16 + r);
    STORE_T(c9,  vo, 1 * 16 + r);
    STORE_T(c10, vo, 2 * 16 + r);
    STORE_T(c11, vo, 3 * 16 + r);
}

// ---------------------------------------------------------------------------
// Attention: one wave per dst edge. lane = half*32 + h*8 + dd.
// ---------------------------------------------------------------------------
__global__ __launch_bounds__(256) void attn_kernel(
    const ushort* __restrict__ q, const ushort* __restrict__ kbuf,
    const ushort* __restrict__ vbuf, const int* __restrict__ adj_src,
    ushort* __restrict__ ao)
{
    const int wid  = (blockIdx.x * 256 + threadIdx.x) >> 6;
    const int lane = threadIdx.x & 63;
    if (wid >= NE) return;
    const int e    = wid;
    const int half = lane >> 5;
    const int l32  = lane & 31;

    const int4 nb = *(const int4*)(adj_src + e * 8 + half * 4);
    const int nbr0 = nb.x, nbr1 = nb.y, nbr2 = nb.z, nbr3 = nb.w;

    ushort2 qu = *(const ushort2*)(q + (size_t)e * 64 + l32 * 2);
    const float q0 = bf2f(qu.x), q1 = bf2f(qu.y);

    ushort2 ku0 = *(const ushort2*)(kbuf + (size_t)nbr0 * 64 + l32 * 2);
    ushort2 ku1 = *(const ushort2*)(kbuf + (size_t)nbr1 * 64 + l32 * 2);
    ushort2 ku2 = *(const ushort2*)(kbuf + (size_t)nbr2 * 64 + l32 * 2);
    ushort2 ku3 = *(const ushort2*)(kbuf + (size_t)nbr3 * 64 + l32 * 2);
    ushort2 vu0 = *(const ushort2*)(vbuf + (size_t)nbr0 * 64 + l32 * 2);
    ushort2 vu1 = *(const ushort2*)(vbuf + (size_t)nbr1 * 64 + l32 * 2);
    ushort2 vu2 = *(const ushort2*)(vbuf + (size_t)nbr2 * 64 + l32 * 2);
    ushort2 vu3 = *(const ushort2*)(vbuf + (size_t)nbr3 * 64 + l32 * 2);

    float s0 = q0 * bf2f(ku0.x) + q1 * bf2f(ku0.y);
    float s1 = q0 * bf2f(ku1.x) + q1 * bf2f(ku1.y);
    float s2 = q0 * bf2f(ku2.x) + q1 * bf2f(ku2.y);
    float s3 = q0 * bf2f(ku3.x) + q1 * bf2f(ku3.y);
    s0 += __shfl_xor(s0, 1); s0 += __shfl_xor(s0, 2); s0 += __shfl_xor(s0, 4);
    s1 += __shfl_xor(s1, 1); s1 += __shfl_xor(s1, 2); s1 += __shfl_xor(s1, 4);
    s2 += __shfl_xor(s2, 1); s2 += __shfl_xor(s2, 2); s2 += __shfl_xor(s2, 4);
    s3 += __shfl_xor(s3, 1); s3 += __shfl_xor(s3, 2); s3 += __shfl_xor(s3, 4);
    s0 *= 0.25f; s1 *= 0.25f; s2 *= 0.25f; s3 *= 0.25f;

    float m = fmaxf(fmaxf(s0, s1), fmaxf(s2, s3));
    m = fmaxf(m, __shfl_xor(m, 32));
    float w0 = __expf(s0 - m), w1 = __expf(s1 - m);
    float w2 = __expf(s2 - m), w3 = __expf(s3 - m);
    float den = w0 + w1 + w2 + w3;
    den += __shfl_xor(den, 32);
    const float inv = 1.f / den;

    float ox = 0.f, oy = 0.f;
    ox = fmaf(w0, bf2f(vu0.x), ox); oy = fmaf(w0, bf2f(vu0.y), oy);
    ox = fmaf(w1, bf2f(vu1.x), ox); oy = fmaf(w1, bf2f(vu1.y), oy);
    ox = fmaf(w2, bf2f(vu2.x), ox); oy = fmaf(w2, bf2f(vu2.y), oy);
    ox = fmaf(w3, bf2f(vu3.x), ox); oy = fmaf(w3, bf2f(vu3.y), oy);
    ox = (ox + __shfl_xor(ox, 32)) * inv;
    oy = (oy + __shfl_xor(oy, 32)) * inv;

    if (lane < 32) {
        ushort2 o;
        o.x = f2bf(ox);
        o.y = f2bf(oy);
        *(ushort2*)(ao + (size_t)e * 64 + l32 * 2) = o;
    }
}

// ---------------------------------------------------------------------------
// Wo GEMM via MFMA + fused residual: out = ef_in + attn(bf16) @ Wo.
// ---------------------------------------------------------------------------
__global__ __launch_bounds__(256) void wo_mfma(
    const float* __restrict__ ef_in, const ushort* __restrict__ attn,
    const ushort* __restrict__ wofrag, float* __restrict__ efo)
{
    const int wave = threadIdx.x >> 6;
    const int lane = threadIdx.x & 63;
    const int r  = lane & 15;
    const int kg = lane >> 4;
    const int e0 = blockIdx.x * 64 + wave * 16;
    const int e  = e0 + r;
    const int ec = (e < NE) ? e : NE - 1;

    short8 af0 = *(const short8*)(attn + (size_t)ec * 64 + kg * 8);
    short8 af1 = *(const short8*)(attn + (size_t)ec * 64 + 32 + kg * 8);

    const char* wf = (const char*)wofrag + (size_t)lane * 16;
    f32x4 d0 = (f32x4)(0.f), d1 = (f32x4)(0.f), d2 = (f32x4)(0.f), d3 = (f32x4)(0.f);
    short8 g0 = *(const short8*)(wf + 0 * 1024);
    short8 g1 = *(const short8*)(wf + 1 * 1024);
    short8 g2 = *(const short8*)(wf + 2 * 1024);
    short8 g3 = *(const short8*)(wf + 3 * 1024);
    MFMA_B16(af0, g0, d0); MFMA_B16(af0, g1, d1);
    MFMA_B16(af0, g2, d2); MFMA_B16(af0, g3, d3);
    g0 = *(const short8*)(wf + 4 * 1024);
    g1 = *(const short8*)(wf + 5 * 1024);
    g2 = *(const short8*)(wf + 6 * 1024);
    g3 = *(const short8*)(wf + 7 * 1024);
    MFMA_B16(af1, g0, d0); MFMA_B16(af1, g1, d1);
    MFMA_B16(af1, g2, d2); MFMA_B16(af1, g3, d3);

    const int orow = e0 + kg * 4;
    #pragma unroll
    for (int t = 0; t < 4; ++t) {
        const f32x4 dd = (t == 0) ? d0 : (t == 1) ? d1 : (t == 2) ? d2 : d3;
        const int c = t * 16 + r;
        #pragma unroll
        for (int j = 0; j < 4; ++j) {
            int row = orow + j;
            if (row < NE) {
                size_t off = (size_t)row * 64 + c;
                efo[off] = dd[j] + ef_in[off];
            }
        }
    }
}

// ---------------------------------------------------------------------------
extern "C" void kernel_launch(void* const* d_in, const int* in_sizes, int n_in,
                              void* d_out, int out_size, void* d_ws, size_t ws_size,
                              hipStream_t stream)
{
    const float* nodef   = (const float*)d_in[0];
    const float* ef      = (const float*)d_in[1];
    const int*   eidx    = (const int*)d_in[2];   // [2,E]
    const int*   adj_src = (const int*)d_in[4];
    const float* l1Wq = (const float*)d_in[6];
    const float* l1Wk = (const float*)d_in[7];
    const float* l1Wv = (const float*)d_in[8];
    const float* l1Wo = (const float*)d_in[9];
    const float* l2Wq = (const float*)d_in[10];
    const float* l2Wk = (const float*)d_in[11];
    const float* l2Wv = (const float*)d_in[12];
    const float* l2Wo = (const float*)d_in[13];

    ushort* q   = (ushort*)d_ws;                 // [E,64] bf16
    ushort* k   = q   + (size_t)NE * 64;
    ushort* v   = k   + (size_t)NE * 64;
    ushort* ao  = v   + (size_t)NE * 64;
    ushort* xp  = ao  + (size_t)NE * 64;         // packed A-frags, 38.4 MB
    ushort* wf1 = xp  + (size_t)NE * 192;        // 36864 ushorts each
    ushort* wf2 = wf1 + 36864;
    ushort* wo1 = wf2 + 36864;                   // 4096 each
    ushort* wo2 = wo1 + 4096;
    float* out = (float*)d_out;

    dim3 blk(256);
    const int gp = (NE * 4 + 255) / 256;  // 1563 (gather_pack)
    const int gq = (NE + 63) / 64;        // 1563 (qkv GEMM)
    const int ga = (NE + 3) / 4;          // 25000
    const int gw = (NE + 63) / 64;        // 1563

    prep_all<<<40, blk, 0, stream>>>(l1Wq, l1Wk, l1Wv, l1Wo,
                                     l2Wq, l2Wk, l2Wv, l2Wo,
                                     wf1, wf2, wo1, wo2);

    // ---- layer 1 ----
    gather_pack<<<gp, blk, 0, stream>>>(ef, nodef, eidx, xp);
    qkv_mfma<<<gq, blk, 0, stream>>>(xp, wf1, q, k, v);
    attn_kernel<<<ga, blk, 0, stream>>>(q, k, v, adj_src, ao);
    wo_mfma<<<gw, blk, 0, stream>>>(ef, ao, wo1, out);
    // ---- layer 2 ----
    gather_pack<<<gp, blk, 0, stream>>>(out, nodef, eidx, xp);
    qkv_mfma<<<gq, blk, 0, stream>>>(xp, wf2, q, k, v);
    attn_kernel<<<ga, blk, 0, stream>>>(q, k, v, adj_src, ao);
    wo_mfma<<<gw, blk, 0, stream>>>(out, ao, wo2, out);
}